// Round 9
// baseline (309.866 us; speedup 1.0000x reference)
//
#include <hip/hip_runtime.h>
#include <math.h>

// ARMA GNN forward: N=100000 nodes, E=1600000 edges, 64 -> 48 -> 40.
// out = log_softmax( relu( A @ (h1@W2) + h1@V2 + b2 ) ), h1 = relu( A @ (x@W1) + x@V1 + b1 )
// A = D^-1/2 (w) D^-1/2.
// R9: column-slab-phased pulls with grid-stride phase ordering: xWp stored as 3
//     column slabs (<=3.2MB each, fits per-XCD 4MB L2); all blocks sweep their
//     node-tiles for slab s before slab s+1 -> gathers become L2 hits. csr rows
//     re-read per phase from the same block -> L2/L1-hot. pull_ls keeps fused
//     softmax via per-block LDS accumulators across phases.

constexpr int F_IN = 64;
constexpr int HIDDEN = 48;
constexpr int N_CLASS = 40;
constexpr int CHUNK = 8192;     // edges per binning block
constexpr int BIN_SHIFT = 9;    // 512 nodes per bin
constexpr int CSR_CAP = 12288;  // LDS stash cap in build_csr (avg bin ~8163)
constexpr int PULL_GRID = 1568; // grid for phased pulls (all-resident, 2 tiles/blk)
constexpr int P2TILES = 2;      // tiles per block in pull2_ls

typedef __attribute__((ext_vector_type(8))) short bf16x8;   // 4 VGPRs
typedef __attribute__((ext_vector_type(4))) float f32x4;    // acc frag

// ---- bf16 pack helpers (RNE) ----------------------------------------------
__device__ __forceinline__ short bfr(float f) {
    unsigned u = __float_as_uint(f);
    return (short)((u + 0x7fffu + ((u >> 16) & 1u)) >> 16);
}
__device__ __forceinline__ unsigned pack_bf2(float a, float b) {
    unsigned ua = __float_as_uint(a), ub = __float_as_uint(b);
    ua = (ua + 0x7fffu + ((ua >> 16) & 1u)) >> 16;
    ub = (ub + 0x7fffu + ((ub >> 16) & 1u)) >> 16;
    return ua | (ub << 16);
}
__device__ __forceinline__ float2 unpack_bf2(unsigned u) {
    return make_float2(__uint_as_float(u << 16), __uint_as_float(u & 0xffff0000u));
}
__device__ __forceinline__ bf16x8 cvt8(float4 f0, float4 f1) {
    bf16x8 r;
    r[0] = bfr(f0.x); r[1] = bfr(f0.y); r[2] = bfr(f0.z); r[3] = bfr(f0.w);
    r[4] = bfr(f1.x); r[5] = bfr(f1.y); r[6] = bfr(f1.z); r[7] = bfr(f1.w);
    return r;
}

// ============================================================================
// MFMA layer-1 GEMM body: 64 nodes/block, 96 cols (W1|V1), K=64.
// xWp written into 3 column slabs [s][n][8 u32].
// ============================================================================
__device__ __forceinline__ void mfma_gemm1_body(char* smem, const float* __restrict__ X,
                                                const float* __restrict__ W,
                                                const float* __restrict__ V,
                                                const float* __restrict__ b,
                                                unsigned* __restrict__ XWp,
                                                float* __restrict__ AGG, int N, int gb,
                                                int tid) {
    short* sWT = (short*)smem;                 // [96][64]
    float* ep = (float*)(smem + 12288);        // [64][96]
    for (int i = tid; i < 96 * 64; i += 256) {
        int c = i >> 6, k = i & 63;
        float v = (c < 48) ? W[k * 48 + c] : V[k * 48 + (c - 48)];
        sWT[i] = bfr(v);
    }
    __syncthreads();

    int lane = tid & 63, wv = tid >> 6;
    int m = lane & 15, quad = lane >> 4;
    int nb0 = gb * 64;
    int n = nb0 + wv * 16 + m;

    bf16x8 a0, a1;
    if (n < N) {
        const float4* xr = (const float4*)(X + (size_t)n * 64 + quad * 8);
        a0 = cvt8(xr[0], xr[1]);
        const float4* xr2 = (const float4*)(X + (size_t)n * 64 + 32 + quad * 8);
        a1 = cvt8(xr2[0], xr2[1]);
    } else {
        for (int j = 0; j < 8; ++j) { a0[j] = 0; a1[j] = 0; }
    }

    f32x4 acc[6];
#pragma unroll
    for (int ct = 0; ct < 6; ++ct) acc[ct] = (f32x4){0.f, 0.f, 0.f, 0.f};
#pragma unroll
    for (int ct = 0; ct < 6; ++ct) {
        bf16x8 b0 = *(const bf16x8*)(sWT + (ct * 16 + m) * 64 + quad * 8);
        bf16x8 b1 = *(const bf16x8*)(sWT + (ct * 16 + m) * 64 + 32 + quad * 8);
        acc[ct] = __builtin_amdgcn_mfma_f32_16x16x32_bf16(a0, b0, acc[ct], 0, 0, 0);
        acc[ct] = __builtin_amdgcn_mfma_f32_16x16x32_bf16(a1, b1, acc[ct], 0, 0, 0);
    }
#pragma unroll
    for (int ct = 0; ct < 6; ++ct)
#pragma unroll
        for (int r = 0; r < 4; ++r)
            ep[(wv * 16 + quad * 4 + r) * 96 + ct * 16 + m] = acc[ct][r];
    __syncthreads();
    for (int i = tid; i < 64 * 24; i += 256) {
        int r = i / 24, c2 = i - r * 24;
        int node = nb0 + r;
        if (node >= N) continue;
        float w0 = ep[r * 96 + 2 * c2], w1 = ep[r * 96 + 2 * c2 + 1];
        int s = c2 >> 3, cc = c2 & 7;  // slab layout [s][n][8]
        XWp[((size_t)s * N + node) * 8 + cc] = pack_bf2(w0, w1);
        float v0 = ep[r * 96 + 48 + 2 * c2], v1 = ep[r * 96 + 48 + 2 * c2 + 1];
        float2 bb = ((const float2*)b)[c2];
        ((float2*)AGG)[node * 24 + c2] = make_float2(v0 + bb.x, v1 + bb.y);
    }
}

// ---- phase A: bin counting (LDS hist -> consecutive-addr atomics) + gemm1 --
__global__ __launch_bounds__(256) void count_gemm1(
    const int* __restrict__ dst, int* __restrict__ binCnt, int E, int nCountBlocks,
    const float* __restrict__ X, const float* __restrict__ W,
    const float* __restrict__ V, const float* __restrict__ b,
    unsigned* __restrict__ XWp, float* __restrict__ AGG, int N) {
    __shared__ char smem[36864];
    if ((int)blockIdx.x < nCountBlocks) {
        int* hist = (int*)smem;
        int tid = threadIdx.x;
        hist[tid] = 0;
        __syncthreads();
        long long e0 = (long long)blockIdx.x * CHUNK;
        int M = (int)min((long long)CHUNK, (long long)E - e0);
        for (int i = tid; i < M; i += 256) atomicAdd(&hist[dst[e0 + i] >> BIN_SHIFT], 1);
        __syncthreads();
        atomicAdd(&binCnt[tid], hist[tid]);  // consecutive words -> coalesced
    } else {
        mfma_gemm1_body(smem, X, W, V, b, XWp, AGG, N,
                        (int)blockIdx.x - nCountBlocks, (int)threadIdx.x);
    }
}

// ---- phase B: exclusive scan of 256 bin counts -----------------------------
__global__ void scan_bins(const int* __restrict__ binCnt, int* __restrict__ binStart,
                          int* __restrict__ binCursor, int* __restrict__ rowPtr,
                          int E, int N) {
    __shared__ int s[256];
    int t = threadIdx.x;
    int v = binCnt[t];
    s[t] = v;
    __syncthreads();
#pragma unroll
    for (int o = 1; o < 256; o <<= 1) {
        int u = (t >= o) ? s[t - o] : 0;
        __syncthreads();
        s[t] += u;
        __syncthreads();
    }
    int excl = s[t] - v;
    binStart[t] = excl;
    binCursor[t] = excl;
    if (t == 0) {
        binStart[256] = E;
        rowPtr[N] = E;
    }
}

// ---- phase C: scatter edges into bin regions (256B runs, line-coalesced) ---
__global__ void binscatter(const int* __restrict__ src, const int* __restrict__ dst,
                           const float* __restrict__ w, int* __restrict__ binCursor,
                           int2* __restrict__ binned, int E) {
    __shared__ int sx[CHUNK];
    __shared__ int sw[CHUNK];
    __shared__ unsigned char sbin[CHUNK];
    __shared__ int hist[256];
    int tid = threadIdx.x;
    hist[tid] = 0;
    __syncthreads();
    long long e0 = (long long)blockIdx.x * CHUNK;
    int M = (int)min((long long)CHUNK, (long long)E - e0);
    for (int i = tid; i < M; i += 256) {
        int d = dst[e0 + i];
        int bn = d >> BIN_SHIFT;
        sx[i] = ((d & 511) << 17) | src[e0 + i];
        sw[i] = __float_as_int(w[e0 + i]);
        sbin[i] = (unsigned char)bn;
        atomicAdd(&hist[bn], 1);
    }
    __syncthreads();
    int base = atomicAdd(&binCursor[tid], hist[tid]);  // consecutive words -> coalesced
    __syncthreads();
    hist[tid] = base;  // reuse as global cursor
    __syncthreads();
    for (int i = tid; i < M; i += 256) {
        int p = atomicAdd(&hist[sbin[i]], 1);  // LDS atomic, cheap
        binned[p] = make_int2(sx[i], sw[i]);
    }
}

// ---- phase D: per-bin LDS counting sort -> CSR (w pre-scaled by dinv[dst]) -
__global__ __launch_bounds__(512) void build_csr(const int2* __restrict__ binned,
                                                 const int* __restrict__ binStart,
                                                 int* __restrict__ rowPtr,
                                                 float* __restrict__ dinv,
                                                 int2* __restrict__ csr, int N) {
    __shared__ int sx[CSR_CAP];
    __shared__ int sw[CSR_CAP];
    __shared__ int cntL[512];
    __shared__ float degL[512];  // deg sums, then dinv values
    __shared__ int scanL[512];
    int b = blockIdx.x, tid = threadIdx.x;
    int e0 = binStart[b], e1 = binStart[b + 1], M = e1 - e0;
    cntL[tid] = 0;
    degL[tid] = 0.f;
    __syncthreads();
    bool fits = (M <= CSR_CAP);
    for (int i = tid; i < M; i += 512) {
        int2 p = binned[e0 + i];
        if (fits) { sx[i] = p.x; sw[i] = p.y; }
        int dl = ((unsigned)p.x) >> 17;
        atomicAdd(&cntL[dl], 1);
        atomicAdd(&degL[dl], __int_as_float(p.y));
    }
    __syncthreads();
    int v = cntL[tid];
    scanL[tid] = v;
    __syncthreads();
#pragma unroll
    for (int o = 1; o < 512; o <<= 1) {
        int u = (tid >= o) ? scanL[tid - o] : 0;
        __syncthreads();
        scanL[tid] += u;
        __syncthreads();
    }
    int excl = scanL[tid] - v;
    int node = (b << BIN_SHIFT) + tid;
    float dg = degL[tid];
    float dv = dg > 0.f ? rsqrtf(dg) : 0.f;
    if (node < N) {
        rowPtr[node] = e0 + excl;
        dinv[node] = dv;
    }
    cntL[tid] = e0 + excl;  // reuse as global write cursor
    degL[tid] = dv;         // reuse as dinv table for write phase
    __syncthreads();
    for (int i = tid; i < M; i += 512) {
        int px, pw;
        if (fits) { px = sx[i]; pw = sw[i]; }
        else { int2 p = binned[e0 + i]; px = p.x; pw = p.y; }
        int dl = ((unsigned)px) >> 17;
        int pos = atomicAdd(&cntL[dl], 1);  // LDS atomic
        float wn = __int_as_float(pw) * degL[dl];  // fold dinv[dst] in now
        csr[pos] = make_int2(px & 0x1FFFF, __float_as_int(wn));
    }
}

// ---- xWp[s][n][8] *= dinv[n]  (layer-1 slabs) ------------------------------
__global__ void scale_xw(unsigned* __restrict__ XWp, const float* __restrict__ dinv,
                         int N) {
    int t = blockIdx.x * blockDim.x + threadIdx.x;
    if (t >= N * 24) return;
    int slabN8 = N * 8;
    int s = t / slabN8;
    int n = (t - s * slabN8) >> 3;
    float dv = dinv[n];
    float2 u = unpack_bf2(XWp[t]);
    XWp[t] = pack_bf2(u.x * dv, u.y * dv);
}

// ============================================================================
// MFMA layer-2 GEMM: 64 nodes/block, 80 cols (W2|V2), K=48 zero-padded to 64.
// xW2p written dinv-scaled into slabs {8,8,4} u32 wide.
// ============================================================================
__global__ __launch_bounds__(256) void gemm2_kernel(
    const float* __restrict__ X, const float* __restrict__ W,
    const float* __restrict__ V, const float* __restrict__ b,
    const float* __restrict__ dinv, unsigned* __restrict__ XWp,
    float* __restrict__ AGG, int N) {
    __shared__ char smem[30720];
    short* sWT = (short*)smem;            // [80][64], k>=48 zero
    float* ep = (float*)(smem + 10240);   // [64][80]
    int tid = threadIdx.x;
    for (int i = tid; i < 80 * 64; i += 256) {
        int c = i >> 6, k = i & 63;
        float v = 0.f;
        if (k < 48) v = (c < 40) ? W[k * 40 + c] : V[k * 40 + (c - 40)];
        sWT[i] = bfr(v);
    }
    __syncthreads();

    int lane = tid & 63, wv = tid >> 6;
    int m = lane & 15, quad = lane >> 4;
    int nb0 = (int)blockIdx.x * 64;
    int n = nb0 + wv * 16 + m;

    bf16x8 a0, a1;
    if (n < N) {
        const float4* xr = (const float4*)(X + (size_t)n * 48 + quad * 8);
        float4 f0 = xr[0], f1 = xr[1];
        f0.x = fmaxf(f0.x, 0.f); f0.y = fmaxf(f0.y, 0.f);
        f0.z = fmaxf(f0.z, 0.f); f0.w = fmaxf(f0.w, 0.f);
        f1.x = fmaxf(f1.x, 0.f); f1.y = fmaxf(f1.y, 0.f);
        f1.z = fmaxf(f1.z, 0.f); f1.w = fmaxf(f1.w, 0.f);
        a0 = cvt8(f0, f1);
        if (quad < 2) {
            const float4* xr2 = (const float4*)(X + (size_t)n * 48 + 32 + quad * 8);
            float4 g0 = xr2[0], g1 = xr2[1];
            g0.x = fmaxf(g0.x, 0.f); g0.y = fmaxf(g0.y, 0.f);
            g0.z = fmaxf(g0.z, 0.f); g0.w = fmaxf(g0.w, 0.f);
            g1.x = fmaxf(g1.x, 0.f); g1.y = fmaxf(g1.y, 0.f);
            g1.z = fmaxf(g1.z, 0.f); g1.w = fmaxf(g1.w, 0.f);
            a1 = cvt8(g0, g1);
        } else {
            for (int j = 0; j < 8; ++j) a1[j] = 0;
        }
    } else {
        for (int j = 0; j < 8; ++j) { a0[j] = 0; a1[j] = 0; }
    }

    f32x4 acc[5];
#pragma unroll
    for (int ct = 0; ct < 5; ++ct) acc[ct] = (f32x4){0.f, 0.f, 0.f, 0.f};
#pragma unroll
    for (int ct = 0; ct < 5; ++ct) {
        bf16x8 b0 = *(const bf16x8*)(sWT + (ct * 16 + m) * 64 + quad * 8);
        bf16x8 b1 = *(const bf16x8*)(sWT + (ct * 16 + m) * 64 + 32 + quad * 8);
        acc[ct] = __builtin_amdgcn_mfma_f32_16x16x32_bf16(a0, b0, acc[ct], 0, 0, 0);
        acc[ct] = __builtin_amdgcn_mfma_f32_16x16x32_bf16(a1, b1, acc[ct], 0, 0, 0);
    }
#pragma unroll
    for (int ct = 0; ct < 5; ++ct)
#pragma unroll
        for (int r = 0; r < 4; ++r)
            ep[(wv * 16 + quad * 4 + r) * 80 + ct * 16 + m] = acc[ct][r];
    __syncthreads();
    for (int i = tid; i < 64 * 20; i += 256) {
        int r = i / 20, c2 = i - r * 20;
        int node = nb0 + r;
        if (node >= N) continue;
        float dv = dinv[node];
        float w0 = ep[r * 80 + 2 * c2], w1 = ep[r * 80 + 2 * c2 + 1];
        unsigned pk = pack_bf2(w0 * dv, w1 * dv);
        if (c2 < 8)       XWp[node * 8 + c2] = pk;
        else if (c2 < 16) XWp[(size_t)N * 8 + node * 8 + (c2 - 8)] = pk;
        else              XWp[(size_t)N * 16 + node * 4 + (c2 - 16)] = pk;
        float v0 = ep[r * 80 + 40 + 2 * c2], v1 = ep[r * 80 + 40 + 2 * c2 + 1];
        float2 bb = ((const float2*)b)[c2];
        ((float2*)AGG)[node * 20 + c2] = make_float2(v0 + bb.x, v1 + bb.y);
    }
}

// ---- 4-way unrolled row accumulate over one slab (stride W u32 per node) ---
template <int W>
__device__ __forceinline__ float2 row_accumW(const unsigned* __restrict__ slab,
                                             const int2* __restrict__ csr, int j,
                                             int end, int c, float2 s) {
    for (; j + 4 <= end; j += 4) {
        int2 p0 = csr[j], p1 = csr[j + 1], p2 = csr[j + 2], p3 = csr[j + 3];
        unsigned u0 = slab[p0.x * W + c];
        unsigned u1 = slab[p1.x * W + c];
        unsigned u2 = slab[p2.x * W + c];
        unsigned u3 = slab[p3.x * W + c];
        float2 x0 = unpack_bf2(u0), x1 = unpack_bf2(u1);
        float2 x2 = unpack_bf2(u2), x3 = unpack_bf2(u3);
        float n0 = __int_as_float(p0.y), n1 = __int_as_float(p1.y);
        float n2 = __int_as_float(p2.y), n3 = __int_as_float(p3.y);
        s.x = fmaf(x0.x, n0, s.x); s.y = fmaf(x0.y, n0, s.y);
        s.x = fmaf(x1.x, n1, s.x); s.y = fmaf(x1.y, n1, s.y);
        s.x = fmaf(x2.x, n2, s.x); s.y = fmaf(x2.y, n2, s.y);
        s.x = fmaf(x3.x, n3, s.x); s.y = fmaf(x3.y, n3, s.y);
    }
    for (; j < end; ++j) {
        int2 p = csr[j];
        float2 xw = unpack_bf2(slab[p.x * W + c]);
        float nr = __int_as_float(p.y);
        s.x = fmaf(xw.x, nr, s.x);
        s.y = fmaf(xw.y, nr, s.y);
    }
    return s;
}

// ---- layer-1 pull, slab-phased: AGG[n] += sum_j xWp[src_j] * nrm_j ---------
// block = 32 nodes x 8 col-pairs; phases over 3 slabs, grid-stride tiles.
__global__ __launch_bounds__(256) void pull1(const unsigned* __restrict__ XWp,
                                             const int2* __restrict__ csr,
                                             const int* __restrict__ rowPtr,
                                             float* __restrict__ AGG, int N,
                                             int nTiles) {
    int tid = threadIdx.x;
    int nl = tid >> 3, c = tid & 7;
#pragma unroll
    for (int s = 0; s < 3; ++s) {
        const unsigned* slab = XWp + (size_t)s * N * 8;
        int cp = s * 8 + c;
        for (int tile = blockIdx.x; tile < nTiles; tile += gridDim.x) {
            int n = tile * 32 + nl;
            if (n >= N) continue;
            int beg = rowPtr[n], end = rowPtr[n + 1];
            float2 acc = ((const float2*)AGG)[n * 24 + cp];
            acc = row_accumW<8>(slab, csr, beg, end, c, acc);
            ((float2*)AGG)[n * 24 + cp] = acc;
        }
    }
}

// ---- layer-2 pull, slab-phased {8,8,4}, fused log_softmax(relu(.)) ---------
// block = 256; up to P2TILES tiles of 32 nodes held in LDS across phases.
__global__ __launch_bounds__(256) void pull2_ls(const unsigned* __restrict__ XWp,
                                                const int2* __restrict__ csr,
                                                const int* __restrict__ rowPtr,
                                                const float* __restrict__ AGGin,
                                                float* __restrict__ out, int N,
                                                int nTiles) {
    __shared__ float2 sacc[P2TILES * 32 * 20];
    __shared__ float sl[P2TILES * 32];
    int tid = threadIdx.x;
    // init accumulators from V-part
#pragma unroll
    for (int tl = 0; tl < P2TILES; ++tl) {
        int tile = blockIdx.x + tl * gridDim.x;
        if (tile >= nTiles) break;
        for (int i = tid; i < 32 * 20; i += 256) {
            int nl = i / 20, c2 = i - nl * 20;
            int n = tile * 32 + nl;
            sacc[tl * 640 + i] =
                (n < N) ? ((const float2*)AGGin)[n * 20 + c2] : make_float2(0.f, 0.f);
        }
    }
    __syncthreads();
#pragma unroll
    for (int s = 0; s < 3; ++s) {
        int w = (s == 2) ? 4 : 8;
        const unsigned* slab = XWp + (size_t)((s == 2) ? N * 16 : s * N * 8);
        int nl = tid / w, c = tid - nl * w;
        if (nl < 32) {
#pragma unroll
            for (int tl = 0; tl < P2TILES; ++tl) {
                int tile = blockIdx.x + tl * gridDim.x;
                if (tile >= nTiles) break;
                int n = tile * 32 + nl;
                if (n >= N) continue;
                int beg = rowPtr[n], end = rowPtr[n + 1];
                float2 acc = make_float2(0.f, 0.f);
                acc = (w == 8) ? row_accumW<8>(slab, csr, beg, end, c, acc)
                               : row_accumW<4>(slab, csr, beg, end, c, acc);
                int cp = (s == 2) ? 16 + c : s * 8 + c;
                float2* p = &sacc[tl * 640 + nl * 20 + cp];  // unique owner
                *p = make_float2(p->x + acc.x, p->y + acc.y);
            }
        }
    }
    __syncthreads();
    if (tid < P2TILES * 32) {
        int tl = tid >> 5, nl = tid & 31;
        int tile = blockIdx.x + tl * gridDim.x;
        if (tile < nTiles) {
            const float2* row = &sacc[tl * 640 + nl * 20];
            float m = 0.f;  // relu floor
            for (int k = 0; k < 20; ++k) {
                float2 v = row[k];
                m = fmaxf(m, fmaxf(v.x, v.y));
            }
            float sum = 0.f;
            for (int k = 0; k < 20; ++k) {
                float2 v = row[k];
                sum += expf(fmaxf(v.x, 0.f) - m) + expf(fmaxf(v.y, 0.f) - m);
            }
            sl[tid] = m + logf(sum);
        }
    }
    __syncthreads();
#pragma unroll
    for (int tl = 0; tl < P2TILES; ++tl) {
        int tile = blockIdx.x + tl * gridDim.x;
        if (tile >= nTiles) break;
        for (int i = tid; i < 32 * 20; i += 256) {
            int nl = i / 20, c2 = i - nl * 20;
            int n = tile * 32 + nl;
            if (n >= N) continue;
            float l = sl[tl * 32 + nl];
            float2 v = sacc[tl * 640 + i];
            ((float2*)out)[n * 20 + c2] =
                make_float2(fmaxf(v.x, 0.f) - l, fmaxf(v.y, 0.f) - l);
        }
    }
}

extern "C" void kernel_launch(void* const* d_in, const int* in_sizes, int n_in,
                              void* d_out, int out_size, void* d_ws, size_t ws_size,
                              hipStream_t stream) {
    const float* x  = (const float*)d_in[0];
    const int*   ei = (const int*)d_in[1];
    const float* ew = (const float*)d_in[2];
    const float* W1 = (const float*)d_in[3];
    const float* V1 = (const float*)d_in[4];
    const float* b1 = (const float*)d_in[5];
    const float* W2 = (const float*)d_in[6];
    const float* V2 = (const float*)d_in[7];
    const float* b2 = (const float*)d_in[8];
    float* out = (float*)d_out;

    const int N = in_sizes[0] / F_IN;
    const int E = in_sizes[2];
    const int* src = ei;
    const int* dst = ei + E;

    char* ws = (char*)d_ws;
    size_t off = 0;
    auto carve = [&](size_t bytes) {
        void* p = ws + off;
        off = (off + bytes + 255) & ~size_t(255);
        return p;
    };
    int*      binCnt    = (int*)carve(256 * 4);
    int*      binStart  = (int*)carve(257 * 4);
    int*      binCursor = (int*)carve(256 * 4);
    int*      rowPtr    = (int*)carve((size_t)(N + 1) * 4);
    float*    dinv      = (float*)carve((size_t)N * 4);
    int2*     binned    = (int2*)carve((size_t)E * 8);
    int2*     csr       = (int2*)carve((size_t)E * 8);
    unsigned* xW1p      = (unsigned*)carve((size_t)N * (HIDDEN / 2) * 4);  // 3 slabs
    float*    agg1      = (float*)carve((size_t)N * HIDDEN * 4);
    float*    agg2      = (float*)carve((size_t)N * N_CLASS * 4);
    unsigned* xW2p      = xW1p;  // xW1p dead before gemm2 writes

    const int B = 256;
    auto cdiv = [](long long a, long long b) { return (int)((a + b - 1) / b); };
    const int nChunks = cdiv(E, CHUNK);
    const int nBins = (N + (1 << BIN_SHIFT) - 1) >> BIN_SHIFT;
    const int nGemmBlocks = cdiv(N, 64);
    const int nTiles = cdiv(N, 32);

    hipMemsetAsync(binCnt, 0, 256 * 4, stream);

    count_gemm1<<<nChunks + nGemmBlocks, B, 0, stream>>>(dst, binCnt, E, nChunks,
                                                         x, W1, V1, b1, xW1p, agg1, N);
    scan_bins<<<1, 256, 0, stream>>>(binCnt, binStart, binCursor, rowPtr, E, N);
    binscatter<<<nChunks, B, 0, stream>>>(src, dst, ew, binCursor, binned, E);
    build_csr<<<nBins, 512, 0, stream>>>(binned, binStart, rowPtr, dinv, csr, N);

    scale_xw<<<cdiv((long long)N * 24, B), B, 0, stream>>>(xW1p, dinv, N);

    pull1<<<PULL_GRID, B, 0, stream>>>(xW1p, csr, rowPtr, agg1, N, nTiles);

    gemm2_kernel<<<nGemmBlocks, B, 0, stream>>>(agg1, W2, V2, b2, dinv, xW2p, agg2, N);

    pull2_ls<<<PULL_GRID, B, 0, stream>>>(xW2p, csr, rowPtr, agg2, out, N, nTiles);
}